// Round 1
// baseline (1706.692 us; speedup 1.0000x reference)
//
#include <hip/hip_runtime.h>

typedef unsigned short ushort_t;
typedef unsigned int uint32;
typedef __attribute__((ext_vector_type(8))) short short8;
typedef __attribute__((ext_vector_type(4))) float f32x4;
typedef __attribute__((ext_vector_type(4))) unsigned int u32x4;

union FragU { u32x4 u; short8 s; };

#define T_DIM 256
#define B_DIM 2048
#define OBS 512
#define HID 32
#define M_ROWS (T_DIM * B_DIM)   // 524288
#define NTILES (M_ROWS / 32)     // 16384

// ---------- numeric helpers ----------
__device__ __forceinline__ ushort_t f2b_rne(float f) {
    uint32 u = __float_as_uint(f);
    u = (u + 0x7FFFu + ((u >> 16) & 1u)) >> 16;
    return (ushort_t)u;
}
__device__ __forceinline__ float b2f(ushort_t s) {
    return __uint_as_float(((uint32)s) << 16);
}
// pack two floats' high halves (truncated bf16) into one dword: (bf(e1)<<16)|bf(e0)
__device__ __forceinline__ uint32 pkbf(float e0, float e1) {
    return __builtin_amdgcn_perm(__float_as_uint(e1), __float_as_uint(e0), 0x07060302u);
}
__device__ __forceinline__ float sigm(float v) {
    return __builtin_amdgcn_rcpf(1.0f + __builtin_amdgcn_exp2f(v * -1.4426950408889634f));
}
__device__ __forceinline__ float tanh_fast(float v) {
    float a = __builtin_fabsf(v);
    float t = __builtin_amdgcn_exp2f(a * -2.8853900817779268f); // e^{-2a}
    float r = (1.0f - t) * __builtin_amdgcn_rcpf(1.0f + t);
    return __builtin_copysignf(r, v);
}

// ---------- kernel 0: weight prep ----------
// Lays out W1,W2 (bf16) and Wf = Wih@W3 (bf16) in exact MFMA B-fragment order:
// flat = ((s*8 + c)*64 + lane)*8 + j  <->  W[n][k], n = c*16+(lane&15), k = s*32+((lane>>4)&3)*8+j
__global__ void setup_kernel(const float* __restrict__ W1, const float* __restrict__ W2,
                             const float* __restrict__ W3, const float* __restrict__ Wih,
                             const float* __restrict__ bih, const float* __restrict__ bhh,
                             const float* __restrict__ b3,
                             ushort_t* __restrict__ w1b, ushort_t* __restrict__ w2b,
                             ushort_t* __restrict__ wfb, float* __restrict__ bfused) {
    int gid = blockIdx.x * 256 + threadIdx.x;
    int nth = gridDim.x * 256;
    for (int e = gid; e < 65536; e += nth) {   // W1b: K=512 -> 16 ksteps
        int j = e & 7, l = (e >> 3) & 63, sc = e >> 9;
        int s = sc >> 3, c = sc & 7;
        int n = c * 16 + (l & 15);
        int k = s * 32 + ((l >> 4) & 3) * 8 + j;
        w1b[e] = f2b_rne(W1[n * 512 + k]);
    }
    for (int e = gid; e < 16384; e += nth) {   // W2b: K=128 -> 4 ksteps
        int j = e & 7, l = (e >> 3) & 63, sc = e >> 9;
        int s = sc >> 3, c = sc & 7;
        int n = c * 16 + (l & 15);
        int k = s * 32 + ((l >> 4) & 3) * 8 + j;
        w2b[e] = f2b_rne(W2[n * 128 + k]);
    }
    for (int e = gid; e < 16384; e += nth) {   // Wf = Wih @ W3 : [128 gates][128 z2]
        int j = e & 7, l = (e >> 3) & 63, sc = e >> 9;
        int s = sc >> 3, c = sc & 7;
        int n = c * 16 + (l & 15);
        int k = s * 32 + ((l >> 4) & 3) * 8 + j;
        float acc = 0.f;
        for (int d = 0; d < 64; d++) acc += Wih[n * 64 + d] * W3[d * 128 + k];
        wfb[e] = f2b_rne(acc);
    }
    for (int e = gid; e < 128; e += nth) {     // bfused = Wih@b3 + bih + bhh
        float s = bih[e] + bhh[e];
        for (int d = 0; d < 64; d++) s += Wih[e * 64 + d] * b3[d];
        bfused[e] = s;
    }
}

// ---------- kernel 1: z1 = tanh(x @ W1^T + b1), written in A-fragment order ----------
// tile = 32 rows; wave per tile; 2 rowtiles x 8 coltiles of 16x16x32 MFMA; K=512.
__global__ __launch_bounds__(256, 2) void passA_kernel(const float* __restrict__ x,
                                                       const float* __restrict__ b1,
                                                       const ushort_t* __restrict__ w1b,
                                                       ushort_t* __restrict__ z1f) {
    __shared__ ushort_t scr[4][32][136];   // pitch 136 elems = 272B (16B multiple)
    int tid = threadIdx.x, wid = tid >> 6, lane = tid & 63;
    int n = lane & 15, q = lane >> 4;
    int tile = blockIdx.x * 4 + wid;

    float bias[8];
#pragma unroll
    for (int c = 0; c < 8; c++) bias[c] = b1[c * 16 + n];

    const float* xr = x + (size_t)(tile * 32 + n) * 512 + q * 8;
    const u32x4* wb = (const u32x4*)w1b;

    f32x4 acc[2][8];
#pragma unroll
    for (int r = 0; r < 2; r++)
#pragma unroll
        for (int c = 0; c < 8; c++) acc[r][c] = (f32x4){0.f, 0.f, 0.f, 0.f};

#pragma unroll 4
    for (int s = 0; s < 16; s++) {
        const f32x4* p0 = (const f32x4*)(xr + s * 32);
        const f32x4* p1 = (const f32x4*)(xr + 16 * 512 + s * 32);
        f32x4 lo0 = p0[0], hi0 = p0[1];
        f32x4 lo1 = p1[0], hi1 = p1[1];
        FragU a0, a1;
        a0.u[0] = pkbf(lo0[0], lo0[1]); a0.u[1] = pkbf(lo0[2], lo0[3]);
        a0.u[2] = pkbf(hi0[0], hi0[1]); a0.u[3] = pkbf(hi0[2], hi0[3]);
        a1.u[0] = pkbf(lo1[0], lo1[1]); a1.u[1] = pkbf(lo1[2], lo1[3]);
        a1.u[2] = pkbf(hi1[0], hi1[1]); a1.u[3] = pkbf(hi1[2], hi1[3]);
#pragma unroll
        for (int c = 0; c < 8; c++) {
            FragU bf; bf.u = wb[(s * 8 + c) * 64 + lane];
            acc[0][c] = __builtin_amdgcn_mfma_f32_16x16x32_bf16(a0.s, bf.s, acc[0][c], 0, 0, 0);
            acc[1][c] = __builtin_amdgcn_mfma_f32_16x16x32_bf16(a1.s, bf.s, acc[1][c], 0, 0, 0);
        }
    }
    // epilogue: tanh -> bf16 -> LDS (C-layout scatter), then read back as A-fragments
#pragma unroll
    for (int r = 0; r < 2; r++)
#pragma unroll
        for (int c = 0; c < 8; c++)
#pragma unroll
            for (int reg = 0; reg < 4; reg++)
                scr[wid][r * 16 + q * 4 + reg][c * 16 + n] =
                    f2b_rne(tanh_fast(acc[r][c][reg] + bias[c]));
    __syncthreads();
    u32x4* zo = (u32x4*)z1f;
#pragma unroll
    for (int rt = 0; rt < 2; rt++)
#pragma unroll
        for (int s = 0; s < 4; s++) {
            u32x4 v = *(const u32x4*)&scr[wid][rt * 16 + n][s * 32 + q * 8];
            zo[((size_t)(tile * 4 + s) * 2 + rt) * 64 + lane] = v;
        }
}

// ---------- kernel 2: z2 = tanh(z1@W2^T+b2); gx = z2@Wf^T + bfused (row-major bf16) ----------
__global__ __launch_bounds__(256, 2) void passBC_kernel(const ushort_t* __restrict__ z1f,
                                                        const float* __restrict__ b2,
                                                        const ushort_t* __restrict__ w2b,
                                                        const ushort_t* __restrict__ wfb,
                                                        const float* __restrict__ bfused,
                                                        ushort_t* __restrict__ gx) {
    __shared__ ushort_t scr[4][32][136];
    int tid = threadIdx.x, wid = tid >> 6, lane = tid & 63;
    int n = lane & 15, q = lane >> 4;
    int tile = blockIdx.x * 4 + wid;

    float bias2[8], biasf[8];
#pragma unroll
    for (int c = 0; c < 8; c++) { bias2[c] = b2[c * 16 + n]; biasf[c] = bfused[c * 16 + n]; }

    const u32x4* za = (const u32x4*)z1f;
    const u32x4* w2 = (const u32x4*)w2b;
    const u32x4* wf = (const u32x4*)wfb;

    f32x4 acc[2][8];
#pragma unroll
    for (int r = 0; r < 2; r++)
#pragma unroll
        for (int c = 0; c < 8; c++) acc[r][c] = (f32x4){0.f, 0.f, 0.f, 0.f};

#pragma unroll
    for (int s = 0; s < 4; s++) {
        FragU a0, a1;
        a0.u = za[(size_t)tile * 512 + (s * 2 + 0) * 64 + lane];
        a1.u = za[(size_t)tile * 512 + (s * 2 + 1) * 64 + lane];
#pragma unroll
        for (int c = 0; c < 8; c++) {
            FragU bf; bf.u = w2[(s * 8 + c) * 64 + lane];
            acc[0][c] = __builtin_amdgcn_mfma_f32_16x16x32_bf16(a0.s, bf.s, acc[0][c], 0, 0, 0);
            acc[1][c] = __builtin_amdgcn_mfma_f32_16x16x32_bf16(a1.s, bf.s, acc[1][c], 0, 0, 0);
        }
    }
#pragma unroll
    for (int r = 0; r < 2; r++)
#pragma unroll
        for (int c = 0; c < 8; c++)
#pragma unroll
            for (int reg = 0; reg < 4; reg++)
                scr[wid][r * 16 + q * 4 + reg][c * 16 + n] =
                    f2b_rne(tanh_fast(acc[r][c][reg] + bias2[c]));
    __syncthreads();
    FragU af[2][4];
#pragma unroll
    for (int rt = 0; rt < 2; rt++)
#pragma unroll
        for (int s = 0; s < 4; s++)
            af[rt][s].u = *(const u32x4*)&scr[wid][rt * 16 + n][s * 32 + q * 8];
    __syncthreads();

    f32x4 acc2[2][8];
#pragma unroll
    for (int r = 0; r < 2; r++)
#pragma unroll
        for (int c = 0; c < 8; c++) acc2[r][c] = (f32x4){0.f, 0.f, 0.f, 0.f};
#pragma unroll
    for (int s = 0; s < 4; s++) {
#pragma unroll
        for (int c = 0; c < 8; c++) {
            FragU bf; bf.u = wf[(s * 8 + c) * 64 + lane];
            acc2[0][c] = __builtin_amdgcn_mfma_f32_16x16x32_bf16(af[0][s].s, bf.s, acc2[0][c], 0, 0, 0);
            acc2[1][c] = __builtin_amdgcn_mfma_f32_16x16x32_bf16(af[1][s].s, bf.s, acc2[1][c], 0, 0, 0);
        }
    }
#pragma unroll
    for (int r = 0; r < 2; r++)
#pragma unroll
        for (int c = 0; c < 8; c++)
#pragma unroll
            for (int reg = 0; reg < 4; reg++)
                scr[wid][r * 16 + q * 4 + reg][c * 16 + n] = f2b_rne(acc2[r][c][reg] + biasf[c]);
    __syncthreads();
    u32x4* go = (u32x4*)gx;
#pragma unroll
    for (int i = 0; i < 8; i++) {
        int ch = i * 64 + lane;
        u32x4 v = *(const u32x4*)&scr[wid][ch >> 4][(ch & 15) * 8];
        go[(size_t)tile * 512 + ch] = v;
    }
}

// ---------- kernel 3: LSTM scan (batch-parallel, no grid sync) ----------
// lane = (half=b, u): wave handles 2 batch elems; Whh rows in 128 VGPRs; h broadcast via ds_swizzle.
#define LSTM_STEP(K) { \
    float hk = __uint_as_float((uint32)__builtin_amdgcn_ds_swizzle((int)hb, ((K) << 5))); \
    ai += wiv[K] * hk; af_ += wfv[K] * hk; ag += wgv[K] * hk; ao += wov[K] * hk; }
#define LSTM_STEP4(B) LSTM_STEP(B) LSTM_STEP(B+1) LSTM_STEP(B+2) LSTM_STEP(B+3)

__global__ __launch_bounds__(256, 1) void lstm_kernel(const ushort_t* __restrict__ gx,
                                                      const int* __restrict__ done,
                                                      const float* __restrict__ h0,
                                                      const float* __restrict__ c0,
                                                      const float* __restrict__ Whh,
                                                      float* __restrict__ hs) {
    int tid = threadIdx.x, wid = tid >> 6, lane = tid & 63;
    int w = blockIdx.x * 4 + wid;
    int half = lane >> 5, u = lane & 31;
    int b = w * 2 + half;

    float wiv[32], wfv[32], wgv[32], wov[32];
    const f32x4* W4 = (const f32x4*)Whh;
#pragma unroll
    for (int j = 0; j < 8; j++) {
        f32x4 v;
        v = W4[(u)      * 8 + j]; wiv[j*4+0]=v[0]; wiv[j*4+1]=v[1]; wiv[j*4+2]=v[2]; wiv[j*4+3]=v[3];
        v = W4[(u + 32) * 8 + j]; wfv[j*4+0]=v[0]; wfv[j*4+1]=v[1]; wfv[j*4+2]=v[2]; wfv[j*4+3]=v[3];
        v = W4[(u + 64) * 8 + j]; wgv[j*4+0]=v[0]; wgv[j*4+1]=v[1]; wgv[j*4+2]=v[2]; wgv[j*4+3]=v[3];
        v = W4[(u + 96) * 8 + j]; wov[j*4+0]=v[0]; wov[j*4+1]=v[1]; wov[j*4+2]=v[2]; wov[j*4+3]=v[3];
    }
    float h = h0[b * 32 + u];
    float c = c0[b * 32 + u];

    // software-pipelined prefetch of gates_x and done
    const ushort_t* gp = gx + (size_t)b * 128;
    ushort_t g0 = gp[u], g1 = gp[u + 32], g2 = gp[u + 64], g3 = gp[u + 96];
    int dn = done[b];

    for (int t = 0; t < 256; t++) {
        float ai = b2f(g0), af_ = b2f(g1), ag = b2f(g2), ao = b2f(g3);
        int dcur = dn;
        int tn = (t < 255) ? (t + 1) : 255;
        const ushort_t* gnp = gx + ((size_t)tn * B_DIM + b) * 128;
        g0 = gnp[u]; g1 = gnp[u + 32]; g2 = gnp[u + 64]; g3 = gnp[u + 96];
        dn = done[tn * B_DIM + b];

        h = dcur ? 0.f : h;
        c = dcur ? 0.f : c;
        uint32 hb = __float_as_uint(h);
        LSTM_STEP4(0)  LSTM_STEP4(4)  LSTM_STEP4(8)  LSTM_STEP4(12)
        LSTM_STEP4(16) LSTM_STEP4(20) LSTM_STEP4(24) LSTM_STEP4(28)

        c = sigm(af_) * c + sigm(ai) * tanh_fast(ag);
        h = sigm(ao) * tanh_fast(c);
        hs[((size_t)t * B_DIM + b) * 32 + u] = h;
    }
}

// ---------- kernel 4: logits head + log_softmax + gather + entropy ----------
__global__ __launch_bounds__(256) void head_kernel(const float* __restrict__ hs,
                                                   const int* __restrict__ action,
                                                   const float* __restrict__ Wlog,
                                                   const float* __restrict__ blog,
                                                   float* __restrict__ out) {
    __shared__ float wl[16][32];
    __shared__ float bl[16];
    int tid = threadIdx.x;
    for (int i = tid; i < 512; i += 256) wl[i >> 5][i & 31] = Wlog[i];
    if (tid < 16) bl[tid] = blog[tid];
    __syncthreads();

    size_t r = (size_t)blockIdx.x * 256 + tid;
    const f32x4* hp = (const f32x4*)(hs + r * 32);
    f32x4 hv[8];
#pragma unroll
    for (int j = 0; j < 8; j++) hv[j] = hp[j];

    float lg[16];
#pragma unroll
    for (int j = 0; j < 16; j++) {
        const f32x4* wp = (const f32x4*)&wl[j][0];
        float s = bl[j];
#pragma unroll
        for (int kq = 0; kq < 8; kq++) {
            f32x4 wv = wp[kq];
            s += wv[0]*hv[kq][0] + wv[1]*hv[kq][1] + wv[2]*hv[kq][2] + wv[3]*hv[kq][3];
        }
        lg[j] = s;
    }
    float m = lg[0];
#pragma unroll
    for (int j = 1; j < 16; j++) m = fmaxf(m, lg[j]);
    float ex[16], se = 0.f;
#pragma unroll
    for (int j = 0; j < 16; j++) {
        ex[j] = __builtin_amdgcn_exp2f((lg[j] - m) * 1.4426950408889634f);
        se += ex[j];
    }
    float inv = __builtin_amdgcn_rcpf(se);
    float lns = 0.6931471805599453f * __builtin_amdgcn_logf(se);
    int a = action[r];
    float lp = 0.f, sp = 0.f;
#pragma unroll
    for (int j = 0; j < 16; j++) {
        float l_j = lg[j] - m - lns;
        sp += ex[j] * l_j;
        lp = (j == a) ? l_j : lp;
    }
    out[r] = (float)a;
    out[(size_t)M_ROWS + r] = lp;
    out[(size_t)2 * M_ROWS + r] = -inv * sp;
}

// ---------- launcher ----------
extern "C" void kernel_launch(void* const* d_in, const int* in_sizes, int n_in,
                              void* d_out, int out_size, void* d_ws, size_t ws_size,
                              hipStream_t stream) {
    const float* x     = (const float*)d_in[0];
    const int*   done  = (const int*)d_in[1];
    const int*   act   = (const int*)d_in[2];
    const float* W1    = (const float*)d_in[3];
    const float* b1    = (const float*)d_in[4];
    const float* W2    = (const float*)d_in[5];
    const float* b2    = (const float*)d_in[6];
    const float* W3    = (const float*)d_in[7];
    const float* b3    = (const float*)d_in[8];
    const float* Wih   = (const float*)d_in[9];
    const float* Whh   = (const float*)d_in[10];
    const float* bih   = (const float*)d_in[11];
    const float* bhh   = (const float*)d_in[12];
    const float* Wlog  = (const float*)d_in[13];
    const float* blog  = (const float*)d_in[14];
    const float* h0    = (const float*)d_in[15];
    const float* c0    = (const float*)d_in[16];

    char* ws = (char*)d_ws;
    // layout: gx bf16 [M][128] | z1f bf16 [M][128] (aliased by hs f32 [M][32] later) | weights
    ushort_t* gx   = (ushort_t*)(ws);
    ushort_t* z1f  = (ushort_t*)(ws + 134217728ull);
    float*    hs   = (float*)(ws + 134217728ull);          // alias: z1 dead after passBC
    ushort_t* w1b  = (ushort_t*)(ws + 268435456ull);
    ushort_t* w2b  = (ushort_t*)(ws + 268435456ull + 131072ull);
    ushort_t* wfb  = (ushort_t*)(ws + 268435456ull + 131072ull + 32768ull);
    float*    bfus = (float*)(ws + 268435456ull + 131072ull + 65536ull);

    setup_kernel<<<64, 256, 0, stream>>>(W1, W2, W3, Wih, bih, bhh, b3, w1b, w2b, wfb, bfus);
    passA_kernel<<<NTILES / 4, 256, 0, stream>>>(x, b1, w1b, z1f);
    passBC_kernel<<<NTILES / 4, 256, 0, stream>>>(z1f, b2, w2b, wfb, bfus, gx);
    lstm_kernel<<<B_DIM / 8, 256, 0, stream>>>(gx, done, h0, c0, Whh, hs);
    head_kernel<<<M_ROWS / 256, 256, 0, stream>>>(hs, act, Wlog, blog, (float*)d_out);
}